// Round 1
// baseline (703.577 us; speedup 1.0000x reference)
//
#include <hip/hip_runtime.h>

#define NTOK 16384

typedef short           bf16x8 __attribute__((ext_vector_type(8)));
typedef float           f32x4  __attribute__((ext_vector_type(4)));
typedef unsigned short  u16x4  __attribute__((ext_vector_type(4)));

// ws float offsets (base 788480 floats ~= 3.08 MB, same as prior passing rounds).
// Optional extension (used only if ws_size permits): xhi/xlo pre-split planes,
// 64 MB each, layout [b][token][channel] bf16.
#define WHI_OFF 0         // 768*256 ushort  (98304 floats)
#define WLO_OFF 98304     // 768*256 ushort
#define CTX_OFF 196608    // 65536 floats (atomic ctx numerator)
#define Z_OFF   262144    // 2048 floats  (atomic z sums)
#define MHI_OFF 264192    // 8*256*256 ushort (262144 floats)
#define MLO_OFF 526336    // 8*256*256 ushort
#define XSP_OFF 788480    // xhi: 8*16384*256 ushort, then xlo same size
#define XPLANE  33554432u // ushorts per plane
#define WS_NEED_BYTES 137371648ull  // 788480*4 + 2*XPLANE*2

union UB8 { unsigned u[4]; bf16x8 v; };

// split fp32 pair into packed hi-bf16 pair and lo-bf16 pair (truncation split;
// residual after hi+lo is ~2^-17 relative — covered by the 3-product MFMA scheme)
__device__ __forceinline__ void split2(float v0, float v1, unsigned& hi, unsigned& lo) {
    unsigned b0 = __float_as_uint(v0), b1 = __float_as_uint(v1);
    unsigned h0 = b0 & 0xffff0000u, h1 = b1 & 0xffff0000u;
    hi = (b0 >> 16) | h1;
    float r0 = v0 - __uint_as_float(h0);
    float r1 = v1 - __uint_as_float(h1);
    lo = (__float_as_uint(r0) >> 16) | (__float_as_uint(r1) & 0xffff0000u);
}

__device__ __forceinline__ unsigned short bf16_trunc(float v) {
    return (unsigned short)(__float_as_uint(v) >> 16);
}
__device__ __forceinline__ float bf16_f(unsigned short u) {
    return __uint_as_float(((unsigned)u) << 16);
}

// prep: split w_qkv [768][256] fp32 -> whi/wlo bf16 planes (A-operand layout, k-contiguous)
__global__ void splitw_k(const float* __restrict__ w,
                         unsigned short* __restrict__ whi,
                         unsigned short* __restrict__ wlo)
{
    const int gid = blockIdx.x * 256 + threadIdx.x;   // 24576 threads x 8 elems
    const float4* wp = (const float4*)w;
    float4 a = wp[gid * 2], b = wp[gid * 2 + 1];
    unsigned h0, h1, h2, h3, l0, l1, l2, l3;
    split2(a.x, a.y, h0, l0);
    split2(a.z, a.w, h1, l1);
    split2(b.x, b.y, h2, l2);
    split2(b.z, b.w, h3, l3);
    ((uint4*)whi)[gid] = make_uint4(h0, h1, h2, h3);
    ((uint4*)wlo)[gid] = make_uint4(l0, l1, l2, l3);
}

// prep: split+transpose x [b][c][n] fp32 -> xhi/xlo [b][n][c] bf16 planes.
// Thread owns 8 channels x 8 tokens; packs channel pairs so stores are uint4.
__global__ void splitx_k(const float* __restrict__ x,
                         unsigned short* __restrict__ xhi,
                         unsigned short* __restrict__ xlo)
{
    const int tid  = threadIdx.x;
    const int b    = blockIdx.x >> 8, tile = blockIdx.x & 255;
    const int n0   = tile * 64;
    const int g    = tid >> 5;        // token group: tokens n0 + g*8 .. +7
    const int cb   = tid & 31;        // channel block: channels cb*8 .. +7
    const int t0   = n0 + g * 8;
    const float* xb = x + (size_t)b * 256 * NTOK;

    float v[8][8];
#pragma unroll
    for (int i = 0; i < 8; ++i) {
        const float* xp = xb + (size_t)(cb * 8 + i) * NTOK + t0;
        float4 a = *(const float4*)xp;
        float4 c = *(const float4*)(xp + 4);
        v[i][0] = a.x; v[i][1] = a.y; v[i][2] = a.z; v[i][3] = a.w;
        v[i][4] = c.x; v[i][5] = c.y; v[i][6] = c.z; v[i][7] = c.w;
    }
    unsigned short* hb = xhi + (size_t)b * NTOK * 256;
    unsigned short* lb = xlo + (size_t)b * NTOK * 256;
#pragma unroll
    for (int j = 0; j < 8; ++j) {
        const int t = t0 + j;
        uint4 hw, lw;
        split2(v[0][j], v[1][j], hw.x, lw.x);
        split2(v[2][j], v[3][j], hw.y, lw.y);
        split2(v[4][j], v[5][j], hw.z, lw.z);
        split2(v[6][j], v[7][j], hw.w, lw.w);
        *(uint4*)(hb + (size_t)t * 256 + cb * 8) = hw;
        *(uint4*)(lb + (size_t)t * 256 + cb * 8) = lw;
    }
}

// K_A: per block: 256 tokens (4 chunks of 64). Per chunk:
//   MFMA GEMM kv[512][64] (split-3 bf16), epilogue bias(+exp for k) -> bf16 LDS
//   tile kvt[tok][512ch] with ch XOR-swizzle ((t&7)<<3), then per-head context
//   GEMM ctx[32][32] += ek . v^T via single-product bf16 MFMA. Atomic flush at end.
// PRESPLIT: B-operand comes from pre-split [b][n][c] bf16 planes as 16B vector
// loads (no scalar loads / no on-the-fly split2) — bit-identical numerics.
template<bool PRESPLIT>
__launch_bounds__(256, 2)
__global__ void kv_ctx_k(const float* __restrict__ x,
                         const unsigned short* __restrict__ xhi,
                         const unsigned short* __restrict__ xlo,
                         const unsigned short* __restrict__ whi,
                         const unsigned short* __restrict__ wlo,
                         const float* __restrict__ bqkv,
                         float* __restrict__ ctxn, float* __restrict__ zsum)
{
    __shared__ unsigned short kvt[32768];   // 64 KB: [tok 64][ch 512] swizzled
    const int tid  = threadIdx.x;
    const int wave = tid >> 6, lane = tid & 63;
    const int quad = lane >> 4, l16 = lane & 15;
    const int b = blockIdx.x >> 6, tile = blockIdx.x & 63;
    const float* xb = x + (size_t)b * 256 * NTOK;
    const unsigned short* xhb = xhi + (size_t)b * NTOK * 256;
    const unsigned short* xlb = xlo + (size_t)b * NTOK * 256;

    // persistent context accumulators: wave owns heads 2w, 2w+1
    f32x4 cacc[2][2][2];
#pragma unroll
    for (int a0 = 0; a0 < 2; ++a0)
#pragma unroll
        for (int a1 = 0; a1 < 2; ++a1)
#pragma unroll
            for (int a2 = 0; a2 < 2; ++a2)
                cacc[a0][a1][a2] = (f32x4){0.f, 0.f, 0.f, 0.f};
    float zacc = 0.f;
    const int zh = tid >> 5, zc = tid & 31;

    for (int chunk = 0; chunk < 4; ++chunk) {
        const int n0 = tile * 256 + chunk * 64;

        for (int half = 0; half < 2; ++half) {          // half0 = k rows, half1 = v rows
            f32x4 acc[4][4];
#pragma unroll
            for (int rt = 0; rt < 4; ++rt)
#pragma unroll
                for (int ct = 0; ct < 4; ++ct) acc[rt][ct] = (f32x4){0.f, 0.f, 0.f, 0.f};

            const int rowbase = 256 + half * 256 + wave * 64;

            for (int k0 = 0; k0 < 256; k0 += 32) {
                bf16x8 ah[4], al[4];
#pragma unroll
                for (int rt = 0; rt < 4; ++rt) {
                    const int off = (rowbase + rt * 16 + l16) * 256 + k0 + quad * 8;
                    ah[rt] = *(const bf16x8*)(whi + off);
                    al[rt] = *(const bf16x8*)(wlo + off);
                }
                bf16x8 bh[4], bl[4];
                if constexpr (PRESPLIT) {
#pragma unroll
                    for (int ct = 0; ct < 4; ++ct) {
                        const size_t off = (size_t)(n0 + ct * 16 + l16) * 256 + k0 + quad * 8;
                        bh[ct] = *(const bf16x8*)(xhb + off);
                        bl[ct] = *(const bf16x8*)(xlb + off);
                    }
                } else {
#pragma unroll
                    for (int ct = 0; ct < 4; ++ct) {
                        const float* xp = xb + (size_t)(k0 + quad * 8) * NTOK + n0 + ct * 16 + l16;
                        UB8 hu, lu;
#pragma unroll
                        for (int p = 0; p < 4; ++p) {
                            float v0 = xp[(2 * p) * NTOK];
                            float v1 = xp[(2 * p + 1) * NTOK];
                            split2(v0, v1, hu.u[p], lu.u[p]);
                        }
                        bh[ct] = hu.v; bl[ct] = lu.v;
                    }
                }
#pragma unroll
                for (int rt = 0; rt < 4; ++rt)
#pragma unroll
                    for (int ct = 0; ct < 4; ++ct) {
                        acc[rt][ct] = __builtin_amdgcn_mfma_f32_16x16x32_bf16(ah[rt], bh[ct], acc[rt][ct], 0, 0, 0);
                        acc[rt][ct] = __builtin_amdgcn_mfma_f32_16x16x32_bf16(al[rt], bh[ct], acc[rt][ct], 0, 0, 0);
                        acc[rt][ct] = __builtin_amdgcn_mfma_f32_16x16x32_bf16(ah[rt], bl[ct], acc[rt][ct], 0, 0, 0);
                    }
            }
            // epilogue: bias (+exp on k half), truncate to bf16, swizzled LDS store
#pragma unroll
            for (int rt = 0; rt < 4; ++rt)
#pragma unroll
                for (int ct = 0; ct < 4; ++ct) {
                    const int t   = ct * 16 + l16;
                    const int s   = (t & 7) << 3;
                    const int ch0 = half * 256 + wave * 64 + rt * 16 + quad * 4;
                    u16x4 st;
#pragma unroll
                    for (int r = 0; r < 4; ++r) {
                        float val = acc[rt][ct][r] + bqkv[256 + ch0 + r];
                        if (half == 0) val = __expf(val);
                        st[r] = bf16_trunc(val);
                    }
                    *(u16x4*)&kvt[t * 512 + (ch0 ^ s)] = st;
                }
        }
        __syncthreads();   // kv tile complete

        // phase 3: ctx[h][c][d] += sum_t ek[c,t]*v[d,t]  (MFMA, A=ek[c][t], B=v[t][d])
#pragma unroll
        for (int hh = 0; hh < 2; ++hh) {
            const int h = wave * 2 + hh;
#pragma unroll
            for (int ks = 0; ks < 2; ++ks) {
                bf16x8 af[2], bf[2];
#pragma unroll
                for (int mi = 0; mi < 2; ++mi)
#pragma unroll
                    for (int j = 0; j < 8; ++j) {
                        const int t = ks * 32 + quad * 8 + j;
                        af[mi][j] = (short)kvt[t * 512 + ((h * 32 + mi * 16 + l16) ^ (j << 3))];
                    }
#pragma unroll
                for (int ni = 0; ni < 2; ++ni)
#pragma unroll
                    for (int j = 0; j < 8; ++j) {
                        const int t = ks * 32 + quad * 8 + j;
                        bf[ni][j] = (short)kvt[t * 512 + ((256 + h * 32 + ni * 16 + l16) ^ (j << 3))];
                    }
#pragma unroll
                for (int mi = 0; mi < 2; ++mi)
#pragma unroll
                    for (int ni = 0; ni < 2; ++ni)
                        cacc[hh][mi][ni] = __builtin_amdgcn_mfma_f32_16x16x32_bf16(af[mi], bf[ni], cacc[hh][mi][ni], 0, 0, 0);
            }
        }
        // z sums (same bf16-rounded ek as the numerator -> consistent ratio)
#pragma unroll 8
        for (int t = 0; t < 64; ++t)
            zacc += bf16_f(kvt[t * 512 + ((zh * 32 + zc) ^ ((t & 7) << 3))]);
        __syncthreads();   // phase-3 reads done before next chunk's epilogue writes
    }

    // flush
#pragma unroll
    for (int hh = 0; hh < 2; ++hh) {
        const int h = wave * 2 + hh;
        float* cp = ctxn + ((size_t)(b * 8 + h)) * 1024;
#pragma unroll
        for (int mi = 0; mi < 2; ++mi)
#pragma unroll
            for (int ni = 0; ni < 2; ++ni)
#pragma unroll
                for (int r = 0; r < 4; ++r) {
                    const int c = mi * 16 + quad * 4 + r;
                    const int d = ni * 16 + l16;
                    atomicAdd(&cp[c * 32 + d], cacc[hh][mi][ni][r]);
                }
    }
    atomicAdd(&zsum[(b * 8 + zh) * 32 + zc], zacc);
}

// K_B: M[b][o][ch=h*32+c] = sum_d w_out[o][h*32+d] * (ctxn[b,h,c,d]/z[b,h,c]) -> hi/lo bf16
__global__ void build_m_k(const float* __restrict__ ctxn, const float* __restrict__ zsum,
                          const float* __restrict__ wout,
                          unsigned short* __restrict__ mhi, unsigned short* __restrict__ mlo)
{
    __shared__ float cl[1024];
    __shared__ float zl[32];
    const int b = blockIdx.x >> 3, h = blockIdx.x & 7;
    const int tid = threadIdx.x;
    if (tid < 32) zl[tid] = 1.0f / zsum[(b * 8 + h) * 32 + tid];
    __syncthreads();
    for (int i = tid; i < 1024; i += 256)
        cl[i] = ctxn[(size_t)(b * 8 + h) * 1024 + i] * zl[i >> 5];
    __syncthreads();
    const int o = tid;
    float wrow[32];
#pragma unroll
    for (int d = 0; d < 32; ++d) wrow[d] = wout[o * 256 + h * 32 + d];
    float m[32];
#pragma unroll 4
    for (int c = 0; c < 32; ++c) {
        float acc = 0.f;
#pragma unroll
        for (int d = 0; d < 32; ++d) acc += wrow[d] * cl[c * 32 + d];
        m[c] = acc;
    }
    unsigned* ph = (unsigned*)(mhi + (size_t)b * 65536 + o * 256 + h * 32);
    unsigned* pl = (unsigned*)(mlo + (size_t)b * 65536 + o * 256 + h * 32);
#pragma unroll
    for (int p = 0; p < 16; ++p) {
        unsigned hu, lu;
        split2(m[2 * p], m[2 * p + 1], hu, lu);
        ph[p] = hu; pl[p] = lu;
    }
}

// K_C: per 64-token tile: GEMM1 q (split-3 MFMA) -> qs fp32 LDS -> channel softmax
//      (in regs) -> packed bf16 q_s aliased into LDS -> GEMM2 (M hi/lo x q_hi) -> out
template<bool PRESPLIT>
__launch_bounds__(256, 2)
__global__ void final_k(const float* __restrict__ x,
                        const unsigned short* __restrict__ xhi,
                        const unsigned short* __restrict__ xlo,
                        const unsigned short* __restrict__ whi,
                        const unsigned short* __restrict__ wlo,
                        const float* __restrict__ bqkv,
                        const unsigned short* __restrict__ mhi,
                        const unsigned short* __restrict__ mlo,
                        const float* __restrict__ bout, float* __restrict__ out)
{
    __shared__ float qs[16384];                 // 64 KB [ch 256][tok 64]
    unsigned short* qb = (unsigned short*)qs;   // aliased lower 32 KB after barrier
    const int tid  = threadIdx.x;
    const int wave = tid >> 6, lane = tid & 63;
    const int quad = lane >> 4, l16 = lane & 15;
    const int b = blockIdx.x >> 8, tile = blockIdx.x & 255;
    const int n0 = tile * 64;
    const float* xb = x + (size_t)b * 256 * NTOK;
    const unsigned short* xhb = xhi + (size_t)b * NTOK * 256;
    const unsigned short* xlb = xlo + (size_t)b * NTOK * 256;

    // ---- GEMM1: q[256][64] ----
    f32x4 acc[4][4];
#pragma unroll
    for (int rt = 0; rt < 4; ++rt)
#pragma unroll
        for (int ct = 0; ct < 4; ++ct) acc[rt][ct] = (f32x4){0.f, 0.f, 0.f, 0.f};

    for (int k0 = 0; k0 < 256; k0 += 32) {
        bf16x8 ah[4], al[4];
#pragma unroll
        for (int rt = 0; rt < 4; ++rt) {
            const int off = (wave * 64 + rt * 16 + l16) * 256 + k0 + quad * 8;
            ah[rt] = *(const bf16x8*)(whi + off);
            al[rt] = *(const bf16x8*)(wlo + off);
        }
        bf16x8 bh[4], bl[4];
        if constexpr (PRESPLIT) {
#pragma unroll
            for (int ct = 0; ct < 4; ++ct) {
                const size_t off = (size_t)(n0 + ct * 16 + l16) * 256 + k0 + quad * 8;
                bh[ct] = *(const bf16x8*)(xhb + off);
                bl[ct] = *(const bf16x8*)(xlb + off);
            }
        } else {
#pragma unroll
            for (int ct = 0; ct < 4; ++ct) {
                const float* xp = xb + (size_t)(k0 + quad * 8) * NTOK + n0 + ct * 16 + l16;
                UB8 hu, lu;
#pragma unroll
                for (int p = 0; p < 4; ++p) {
                    float v0 = xp[(2 * p) * NTOK];
                    float v1 = xp[(2 * p + 1) * NTOK];
                    split2(v0, v1, hu.u[p], lu.u[p]);
                }
                bh[ct] = hu.v; bl[ct] = lu.v;
            }
        }
#pragma unroll
        for (int rt = 0; rt < 4; ++rt)
#pragma unroll
            for (int ct = 0; ct < 4; ++ct) {
                acc[rt][ct] = __builtin_amdgcn_mfma_f32_16x16x32_bf16(ah[rt], bh[ct], acc[rt][ct], 0, 0, 0);
                acc[rt][ct] = __builtin_amdgcn_mfma_f32_16x16x32_bf16(al[rt], bh[ct], acc[rt][ct], 0, 0, 0);
                acc[rt][ct] = __builtin_amdgcn_mfma_f32_16x16x32_bf16(ah[rt], bl[ct], acc[rt][ct], 0, 0, 0);
            }
    }
#pragma unroll
    for (int rt = 0; rt < 4; ++rt)
#pragma unroll
        for (int ct = 0; ct < 4; ++ct) {
            const int t = ct * 16 + l16;
#pragma unroll
            for (int r = 0; r < 4; ++r) {
                const int ch = wave * 64 + rt * 16 + quad * 4 + r;
                qs[ch * 64 + t] = acc[rt][ct][r] + bqkv[ch];
            }
        }
    __syncthreads();

    // ---- softmax over 32 channels per head, pack bf16 into regs ----
    unsigned qp[2][16];
#pragma unroll
    for (int rep = 0; rep < 2; ++rep) {
        const int h = (tid >> 6) + rep * 4;
        const int t = tid & 63;
        float e[32];
        float ssum = 0.f;
#pragma unroll
        for (int c = 0; c < 32; ++c) {
            e[c] = __expf(qs[(h * 32 + c) * 64 + t]);
            ssum += e[c];
        }
        const float rinv = 1.0f / ssum;
#pragma unroll
        for (int p = 0; p < 16; ++p) {
            unsigned u0 = (unsigned)bf16_trunc(e[2 * p] * rinv);
            unsigned u1 = (unsigned)bf16_trunc(e[2 * p + 1] * rinv);
            qp[rep][p] = u0 | (u1 << 16);
        }
    }
    __syncthreads();   // all qs reads complete before aliasing writes
#pragma unroll
    for (int rep = 0; rep < 2; ++rep) {
        const int h = (tid >> 6) + rep * 4;
        const int t = tid & 63;
        const int s = (t & 7) << 3;
#pragma unroll
        for (int g = 0; g < 4; ++g) {
            UB8 w8;
#pragma unroll
            for (int p = 0; p < 4; ++p) w8.u[p] = qp[rep][g * 4 + p];
            *(bf16x8*)&qb[t * 256 + ((h * 32 + g * 8) ^ s)] = w8.v;
        }
    }
    __syncthreads();

    // ---- GEMM2: out[256][64] = M (hi/lo) x q_s (hi) ----
#pragma unroll
    for (int rt = 0; rt < 4; ++rt)
#pragma unroll
        for (int ct = 0; ct < 4; ++ct) acc[rt][ct] = (f32x4){0.f, 0.f, 0.f, 0.f};
    const unsigned short* mhb = mhi + (size_t)b * 65536;
    const unsigned short* mlb = mlo + (size_t)b * 65536;

    for (int k0 = 0; k0 < 256; k0 += 32) {
        bf16x8 ah[4], al[4];
#pragma unroll
        for (int rt = 0; rt < 4; ++rt) {
            const int off = (wave * 64 + rt * 16 + l16) * 256 + k0 + quad * 8;
            ah[rt] = *(const bf16x8*)(mhb + off);
            al[rt] = *(const bf16x8*)(mlb + off);
        }
        bf16x8 bq[4];
#pragma unroll
        for (int ct = 0; ct < 4; ++ct) {
            const int t = ct * 16 + l16;
            const int s = (t & 7) << 3;
            bq[ct] = *(const bf16x8*)&qb[t * 256 + ((k0 + quad * 8) ^ s)];
        }
#pragma unroll
        for (int rt = 0; rt < 4; ++rt)
#pragma unroll
            for (int ct = 0; ct < 4; ++ct) {
                acc[rt][ct] = __builtin_amdgcn_mfma_f32_16x16x32_bf16(ah[rt], bq[ct], acc[rt][ct], 0, 0, 0);
                acc[rt][ct] = __builtin_amdgcn_mfma_f32_16x16x32_bf16(al[rt], bq[ct], acc[rt][ct], 0, 0, 0);
            }
    }

    float* ob = out + (size_t)b * 256 * NTOK;
#pragma unroll
    for (int rt = 0; rt < 4; ++rt)
#pragma unroll
        for (int ct = 0; ct < 4; ++ct) {
            const int t = ct * 16 + l16;
#pragma unroll
            for (int r = 0; r < 4; ++r) {
                const int o = wave * 64 + rt * 16 + quad * 4 + r;
                ob[(size_t)o * NTOK + n0 + t] = acc[rt][ct][r] + bout[o];
            }
        }
}

extern "C" void kernel_launch(void* const* d_in, const int* in_sizes, int n_in,
                              void* d_out, int out_size, void* d_ws, size_t ws_size,
                              hipStream_t stream)
{
    (void)in_sizes; (void)n_in; (void)out_size;
    const float* x    = (const float*)d_in[0];
    const float* wqkv = (const float*)d_in[1];
    const float* bqkv = (const float*)d_in[2];
    const float* wout = (const float*)d_in[3];
    const float* bout = (const float*)d_in[4];
    float* out = (float*)d_out;
    float* ws  = (float*)d_ws;

    unsigned short* whi = (unsigned short*)(ws + WHI_OFF);
    unsigned short* wlo = (unsigned short*)(ws + WLO_OFF);
    float*          ctx = ws + CTX_OFF;
    float*          zs  = ws + Z_OFF;
    unsigned short* mhi = (unsigned short*)(ws + MHI_OFF);
    unsigned short* mlo = (unsigned short*)(ws + MLO_OFF);
    unsigned short* xhi = (unsigned short*)(ws + XSP_OFF);
    unsigned short* xlo = xhi + XPLANE;

    const bool presplit = ws_size >= WS_NEED_BYTES;

    hipMemsetAsync(ctx, 0, (65536 + 2048) * sizeof(float), stream);
    splitw_k<<<96, 256, 0, stream>>>(wqkv, whi, wlo);
    if (presplit) {
        splitx_k<<<2048, 256, 0, stream>>>(x, xhi, xlo);
        kv_ctx_k<true><<<512, 256, 0, stream>>>(x, xhi, xlo, whi, wlo, bqkv, ctx, zs);
        build_m_k<<<64, 256, 0, stream>>>(ctx, zs, wout, mhi, mlo);
        final_k<true><<<2048, 256, 0, stream>>>(x, xhi, xlo, whi, wlo, bqkv, mhi, mlo, bout, out);
    } else {
        kv_ctx_k<false><<<512, 256, 0, stream>>>(x, nullptr, nullptr, whi, wlo, bqkv, ctx, zs);
        build_m_k<<<64, 256, 0, stream>>>(ctx, zs, wout, mhi, mlo);
        final_k<false><<<2048, 256, 0, stream>>>(x, nullptr, nullptr, whi, wlo, bqkv, mhi, mlo, bout, out);
    }
}

// Round 2
// 419.514 us; speedup vs baseline: 1.6771x; 1.6771x over previous
//
#include <hip/hip_runtime.h>

#define NTOK 16384

typedef short           bf16x8 __attribute__((ext_vector_type(8)));
typedef float           f32x4  __attribute__((ext_vector_type(4)));
typedef unsigned short  u16x4  __attribute__((ext_vector_type(4)));

// ws float offsets (total ~3.08 MB, same footprint as round-0 passing kernel)
#define WHI_OFF 0         // 768*256 ushort (fragment-major)
#define WLO_OFF 98304
#define CTX_OFF 196608    // 65536 floats (atomic ctx numerator)
#define Z_OFF   262144    // 2048 floats  (atomic z sums)
#define MHI_OFF 264192    // 8*256*256 ushort (fragment-major)
#define MLO_OFF 526336

union UB8 { unsigned u[4]; bf16x8 v; };

// async 16B global->LDS (dest = wave-uniform base + lane*16)
#define GLL16(src, dst)                                                          \
    __builtin_amdgcn_global_load_lds(                                            \
        (const __attribute__((address_space(1))) unsigned*)(src),                \
        (__attribute__((address_space(3))) unsigned*)(dst), 16, 0, 0)

// split fp32 pair into packed hi-bf16 pair and lo-bf16 pair (truncation split;
// residual after hi+lo is ~2^-17 relative — covered by the 3-product MFMA scheme)
__device__ __forceinline__ void split2(float v0, float v1, unsigned& hi, unsigned& lo) {
    unsigned b0 = __float_as_uint(v0), b1 = __float_as_uint(v1);
    unsigned h0 = b0 & 0xffff0000u, h1 = b1 & 0xffff0000u;
    hi = (b0 >> 16) | h1;
    float r0 = v0 - __uint_as_float(h0);
    float r1 = v1 - __uint_as_float(h1);
    lo = (__float_as_uint(r0) >> 16) | (__float_as_uint(r1) & 0xffff0000u);
}

__device__ __forceinline__ unsigned short bf16_trunc(float v) {
    return (unsigned short)(__float_as_uint(v) >> 16);
}
__device__ __forceinline__ float bf16_f(unsigned short u) {
    return __uint_as_float(((unsigned)u) << 16);
}

// prep: split w_qkv [768][256] fp32 -> whi/wlo bf16, FRAGMENT-MAJOR layout:
// uint4 index = ((row>>4)*8 + (ch>>5))*64 + ((ch>>3)&3)*16 + (row&15)
// so one wave's A-fragment load (lane = quad*16+l16) is 64 lanes x 16B contiguous.
__global__ void splitw_k(const float* __restrict__ w,
                         unsigned short* __restrict__ whi,
                         unsigned short* __restrict__ wlo)
{
    const int gid = blockIdx.x * 256 + threadIdx.x;   // 24576 threads x 8 ch
    const int row = gid >> 5, c8 = gid & 31;          // c8 = ch/8
    const float* wp = w + row * 256 + c8 * 8;
    float4 a = *(const float4*)wp;
    float4 b = *(const float4*)(wp + 4);
    uint4 hv, lv;
    split2(a.x, a.y, hv.x, lv.x);
    split2(a.z, a.w, hv.y, lv.y);
    split2(b.x, b.y, hv.z, lv.z);
    split2(b.z, b.w, hv.w, lv.w);
    const int didx = ((row >> 4) * 8 + (c8 >> 2)) * 64 + (c8 & 3) * 16 + (row & 15);
    ((uint4*)whi)[didx] = hv;
    ((uint4*)wlo)[didx] = lv;
}

// fragment-major A load: a[rt] = rows (tb0+rt)*16 + l16, ch kblk*32 + quad*8 ..+7
__device__ __forceinline__ void loadA(const unsigned short* __restrict__ w,
                                      int tb0, int kblk, int lane, bf16x8 a[4])
{
#pragma unroll
    for (int rt = 0; rt < 4; ++rt)
        a[rt] = *(const bf16x8*)(w + (((tb0 + rt) * 8 + kblk) * 64 + lane) * 8);
}

// stage x[k0..k0+31][n0..n0+63] fp32 (8 KB) into LDS buffer [32 rows][64 tok]
__device__ __forceinline__ void stageX(const float* __restrict__ xb, int k0, int n0,
                                       float* __restrict__ xsbuf, int tid)
{
    const int r = tid >> 4, s = tid & 15;
    const float* src0 = xb + (size_t)(k0 + r) * NTOK + n0 + s * 4;
    char* lds_base = (char*)xsbuf + (tid >> 6) * 1024;   // wave-uniform base
    GLL16(src0, lds_base);
    GLL16(src0 + (size_t)16 * NTOK, lds_base + 4096);
}

// build B fragments (split-3) from the staged fp32 tile — bit-identical to
// the original on-the-fly split of global x.
__device__ __forceinline__ void buildB(const float* __restrict__ xs,
                                       int quad, int l16, bf16x8 bh[4], bf16x8 bl[4])
{
#pragma unroll
    for (int ct = 0; ct < 4; ++ct) {
        UB8 hu, lu;
#pragma unroll
        for (int p = 0; p < 4; ++p) {
            float v0 = xs[(quad * 8 + 2 * p) * 64 + ct * 16 + l16];
            float v1 = xs[(quad * 8 + 2 * p + 1) * 64 + ct * 16 + l16];
            split2(v0, v1, hu.u[p], lu.u[p]);
        }
        bh[ct] = hu.v; bl[ct] = lu.v;
    }
}

__device__ __forceinline__ void mfma48(f32x4 acc[4][4],
                                       const bf16x8 ah[4], const bf16x8 al[4],
                                       const bf16x8 bh[4], const bf16x8 bl[4])
{
    __builtin_amdgcn_s_setprio(1);
#pragma unroll
    for (int rt = 0; rt < 4; ++rt)
#pragma unroll
        for (int ct = 0; ct < 4; ++ct) {
            acc[rt][ct] = __builtin_amdgcn_mfma_f32_16x16x32_bf16(ah[rt], bh[ct], acc[rt][ct], 0, 0, 0);
            acc[rt][ct] = __builtin_amdgcn_mfma_f32_16x16x32_bf16(al[rt], bh[ct], acc[rt][ct], 0, 0, 0);
            acc[rt][ct] = __builtin_amdgcn_mfma_f32_16x16x32_bf16(ah[rt], bl[ct], acc[rt][ct], 0, 0, 0);
        }
    __builtin_amdgcn_s_setprio(0);
}

// K_A: per block: 256 tokens (4 chunks of 64). GEMM kv[512][64] with x-tile
// staged in LDS (global_load_lds, double-buffered, aliased into dead kvt
// space), then per-head ctx GEMM from channel-major swizzled kvt.
__launch_bounds__(256, 2)
__global__ void kv_ctx_k(const float* __restrict__ x,
                         const unsigned short* __restrict__ whi,
                         const unsigned short* __restrict__ wlo,
                         const float* __restrict__ bqkv,
                         float* __restrict__ ctxn, float* __restrict__ zsum)
{
    // 64 KB. kvt layout: CHANNEL-major [ch 512][tok 64], u16 addr =
    // ch*64 + (t ^ ((ch&7)<<3)).  Bytes [32768,49152) double as the x-stage
    // buffers during the GEMM k-loops (that ch range 256..383 is dead then).
    __shared__ __align__(16) unsigned short kvt[32768];
    float* xs0 = (float*)((char*)kvt + 32768);
    float* xs1 = (float*)((char*)kvt + 40960);

    const int tid  = threadIdx.x;
    const int wave = tid >> 6, lane = tid & 63;
    const int quad = lane >> 4, l16 = lane & 15;
    const int b = blockIdx.x >> 6, tile = blockIdx.x & 63;
    const float* xb = x + (size_t)b * 256 * NTOK;

    f32x4 cacc[2][2][2];
#pragma unroll
    for (int a0 = 0; a0 < 2; ++a0)
#pragma unroll
        for (int a1 = 0; a1 < 2; ++a1)
#pragma unroll
            for (int a2 = 0; a2 < 2; ++a2)
                cacc[a0][a1][a2] = (f32x4){0.f, 0.f, 0.f, 0.f};
    float zacc = 0.f;

    for (int chunk = 0; chunk < 4; ++chunk) {
        const int n0 = tile * 256 + chunk * 64;

        for (int half = 0; half < 2; ++half) {          // half0 = k rows, half1 = v rows
            f32x4 acc[4][4];
#pragma unroll
            for (int rt = 0; rt < 4; ++rt)
#pragma unroll
                for (int ct = 0; ct < 4; ++ct) acc[rt][ct] = (f32x4){0.f, 0.f, 0.f, 0.f};

            const int tb0 = (256 + half * 256 + wave * 64) >> 4;   // row-tile base

            stageX(xb, 0, n0, xs0, tid);
            __syncthreads();                            // xs0 staged
#pragma unroll
            for (int it = 0; it < 8; ++it) {
                float* xsc = (it & 1) ? xs1 : xs0;
                float* xsn = (it & 1) ? xs0 : xs1;
                if (it < 7) stageX(xb, (it + 1) * 32, n0, xsn, tid);  // async next
                bf16x8 ah[4], al[4];
                loadA(whi, tb0, it, lane, ah);
                loadA(wlo, tb0, it, lane, al);
                bf16x8 bh[4], bl[4];
                buildB(xsc, quad, l16, bh, bl);
                mfma48(acc, ah, al, bh, bl);
                __syncthreads();                        // drains next stage; buffers swap
            }
            // epilogue: bias (+exp on k half) -> bf16 -> channel-major swizzled kvt
#pragma unroll
            for (int rt = 0; rt < 4; ++rt)
#pragma unroll
                for (int ct = 0; ct < 4; ++ct) {
                    const int t = ct * 16 + l16;
#pragma unroll
                    for (int r = 0; r < 4; ++r) {
                        const int ch = half * 256 + wave * 64 + rt * 16 + quad * 4 + r;
                        float val = acc[rt][ct][r] + bqkv[256 + ch];
                        if (half == 0) val = __expf(val);
                        kvt[ch * 64 + (t ^ ((ch & 7) << 3))] = bf16_trunc(val);
                    }
                }
        }
        __syncthreads();   // kv tile complete

        // phase 3: ctx[h][c][d] += sum_t ek[c,t]*v[d,t] — b128 fragment reads
#pragma unroll
        for (int hh = 0; hh < 2; ++hh) {
            const int h = wave * 2 + hh;
#pragma unroll
            for (int ks = 0; ks < 2; ++ks) {
                const int tb = ks * 32 + quad * 8;
                bf16x8 af[2], bfr[2];
#pragma unroll
                for (int mi = 0; mi < 2; ++mi) {
                    const int ch = h * 32 + mi * 16 + l16;
                    af[mi] = *(const bf16x8*)&kvt[ch * 64 + (tb ^ ((ch & 7) << 3))];
                }
#pragma unroll
                for (int ni = 0; ni < 2; ++ni) {
                    const int ch = 256 + h * 32 + ni * 16 + l16;
                    bfr[ni] = *(const bf16x8*)&kvt[ch * 64 + (tb ^ ((ch & 7) << 3))];
                }
#pragma unroll
                for (int mi = 0; mi < 2; ++mi)
#pragma unroll
                    for (int ni = 0; ni < 2; ++ni)
                        cacc[hh][mi][ni] = __builtin_amdgcn_mfma_f32_16x16x32_bf16(af[mi], bfr[ni], cacc[hh][mi][ni], 0, 0, 0);
            }
        }
        // z sums (same bf16-rounded ek as numerator). ch == tid (0..255).
        {
            const int ch = tid;
            const int zs = (ch & 7) << 3;
#pragma unroll
            for (int t8 = 0; t8 < 8; ++t8) {
                bf16x8 v8 = *(const bf16x8*)&kvt[ch * 64 + ((t8 * 8) ^ zs)];
#pragma unroll
                for (int u = 0; u < 8; ++u) zacc += bf16_f((unsigned short)v8[u]);
            }
        }
        __syncthreads();   // phase-3/z reads done before next chunk's writes
    }

    // flush
#pragma unroll
    for (int hh = 0; hh < 2; ++hh) {
        const int h = wave * 2 + hh;
        float* cp = ctxn + ((size_t)(b * 8 + h)) * 1024;
#pragma unroll
        for (int mi = 0; mi < 2; ++mi)
#pragma unroll
            for (int ni = 0; ni < 2; ++ni)
#pragma unroll
                for (int r = 0; r < 4; ++r) {
                    const int c = mi * 16 + quad * 4 + r;
                    const int d = ni * 16 + l16;
                    atomicAdd(&cp[c * 32 + d], cacc[hh][mi][ni][r]);
                }
    }
    atomicAdd(&zsum[(b * 8 + (tid >> 5)) * 32 + (tid & 31)], zacc);
}

// K_B: M[b][o][ch] = sum_d w_out[o][h*32+d] * (ctx/z) -> hi/lo bf16, fragment-major
__global__ void build_m_k(const float* __restrict__ ctxn, const float* __restrict__ zsum,
                          const float* __restrict__ wout,
                          unsigned short* __restrict__ mhi, unsigned short* __restrict__ mlo)
{
    __shared__ float cl[1024];
    __shared__ float zl[32];
    const int b = blockIdx.x >> 3, h = blockIdx.x & 7;
    const int tid = threadIdx.x;
    if (tid < 32) zl[tid] = 1.0f / zsum[(b * 8 + h) * 32 + tid];
    __syncthreads();
    for (int i = tid; i < 1024; i += 256)
        cl[i] = ctxn[(size_t)(b * 8 + h) * 1024 + i] * zl[i >> 5];
    __syncthreads();
    const int o = tid;
    float wrow[32];
#pragma unroll
    for (int d = 0; d < 32; ++d) wrow[d] = wout[o * 256 + h * 32 + d];
    float m[32];
#pragma unroll 4
    for (int c = 0; c < 32; ++c) {
        float acc = 0.f;
#pragma unroll
        for (int d = 0; d < 32; ++d) acc += wrow[d] * cl[c * 32 + d];
        m[c] = acc;
    }
    uint4* dh = (uint4*)mhi + (size_t)b * 8192;
    uint4* dl = (uint4*)mlo + (size_t)b * 8192;
#pragma unroll
    for (int q = 0; q < 4; ++q) {
        uint4 hv, lv;
        split2(m[q * 8 + 0], m[q * 8 + 1], hv.x, lv.x);
        split2(m[q * 8 + 2], m[q * 8 + 3], hv.y, lv.y);
        split2(m[q * 8 + 4], m[q * 8 + 5], hv.z, lv.z);
        split2(m[q * 8 + 6], m[q * 8 + 7], hv.w, lv.w);
        const int di = ((o >> 4) * 8 + h) * 64 + q * 16 + (o & 15);
        dh[di] = hv; dl[di] = lv;
    }
}

// K_C: GEMM1 q (staged x) -> qs fp32 LDS -> channel softmax -> packed bf16 q_s
//      aliased into LDS -> GEMM2 (fragment-major M hi/lo x q_hi) -> out
__launch_bounds__(256, 2)
__global__ void final_k(const float* __restrict__ x,
                        const unsigned short* __restrict__ whi,
                        const unsigned short* __restrict__ wlo,
                        const float* __restrict__ bqkv,
                        const unsigned short* __restrict__ mhi,
                        const unsigned short* __restrict__ mlo,
                        const float* __restrict__ bout, float* __restrict__ out)
{
    __shared__ __align__(16) float qs[16384];   // 64 KB [ch 256][tok 64]
    unsigned short* qb = (unsigned short*)qs;   // aliased lower 32 KB after barrier
    float* xs0 = qs + 8192;                     // bytes [32768,40960): x-stage buf0
    float* xs1 = qs + 10240;                    // bytes [40960,49152): x-stage buf1
    const int tid  = threadIdx.x;
    const int wave = tid >> 6, lane = tid & 63;
    const int quad = lane >> 4, l16 = lane & 15;
    const int b = blockIdx.x >> 8, tile = blockIdx.x & 255;
    const int n0 = tile * 64;
    const float* xb = x + (size_t)b * 256 * NTOK;

    // ---- GEMM1: q[256][64] ----
    f32x4 acc[4][4];
#pragma unroll
    for (int rt = 0; rt < 4; ++rt)
#pragma unroll
        for (int ct = 0; ct < 4; ++ct) acc[rt][ct] = (f32x4){0.f, 0.f, 0.f, 0.f};

    stageX(xb, 0, n0, xs0, tid);
    __syncthreads();
#pragma unroll
    for (int it = 0; it < 8; ++it) {
        float* xsc = (it & 1) ? xs1 : xs0;
        float* xsn = (it & 1) ? xs0 : xs1;
        if (it < 7) stageX(xb, (it + 1) * 32, n0, xsn, tid);
        bf16x8 ah[4], al[4];
        loadA(whi, wave * 4, it, lane, ah);
        loadA(wlo, wave * 4, it, lane, al);
        bf16x8 bh[4], bl[4];
        buildB(xsc, quad, l16, bh, bl);
        mfma48(acc, ah, al, bh, bl);
        __syncthreads();
    }
    // epilogue (xs region dead now; overwritten with real q values)
#pragma unroll
    for (int rt = 0; rt < 4; ++rt)
#pragma unroll
        for (int ct = 0; ct < 4; ++ct) {
            const int t = ct * 16 + l16;
#pragma unroll
            for (int r = 0; r < 4; ++r) {
                const int ch = wave * 64 + rt * 16 + quad * 4 + r;
                qs[ch * 64 + t] = acc[rt][ct][r] + bqkv[ch];
            }
        }
    __syncthreads();

    // ---- softmax over 32 channels per head, pack bf16 into regs ----
    unsigned qp[2][16];
#pragma unroll
    for (int rep = 0; rep < 2; ++rep) {
        const int h = (tid >> 6) + rep * 4;
        const int t = tid & 63;
        float e[32];
        float ssum = 0.f;
#pragma unroll
        for (int c = 0; c < 32; ++c) {
            e[c] = __expf(qs[(h * 32 + c) * 64 + t]);
            ssum += e[c];
        }
        const float rinv = 1.0f / ssum;
#pragma unroll
        for (int p = 0; p < 16; ++p) {
            unsigned u0 = (unsigned)bf16_trunc(e[2 * p] * rinv);
            unsigned u1 = (unsigned)bf16_trunc(e[2 * p + 1] * rinv);
            qp[rep][p] = u0 | (u1 << 16);
        }
    }
    __syncthreads();   // all qs reads complete before aliasing writes
#pragma unroll
    for (int rep = 0; rep < 2; ++rep) {
        const int h = (tid >> 6) + rep * 4;
        const int t = tid & 63;
        const int s = (t & 7) << 3;
#pragma unroll
        for (int g = 0; g < 4; ++g) {
            UB8 w8;
#pragma unroll
            for (int p = 0; p < 4; ++p) w8.u[p] = qp[rep][g * 4 + p];
            *(bf16x8*)&qb[t * 256 + ((h * 32 + g * 8) ^ s)] = w8.v;
        }
    }
    __syncthreads();

    // ---- GEMM2: out[256][64] = M (hi/lo) x q_s (hi), prefetch depth-1 ----
#pragma unroll
    for (int rt = 0; rt < 4; ++rt)
#pragma unroll
        for (int ct = 0; ct < 4; ++ct) acc[rt][ct] = (f32x4){0.f, 0.f, 0.f, 0.f};
    const unsigned short* mhb = mhi + (size_t)b * 65536;
    const unsigned short* mlb = mlo + (size_t)b * 65536;

    bf16x8 mah[2][4], mal[2][4];
    loadA(mhb, wave * 4, 0, lane, mah[0]);
    loadA(mlb, wave * 4, 0, lane, mal[0]);
#pragma unroll
    for (int it = 0; it < 8; ++it) {
        const int cb = it & 1, nb = cb ^ 1;
        if (it < 7) {
            loadA(mhb, wave * 4, it + 1, lane, mah[nb]);
            loadA(mlb, wave * 4, it + 1, lane, mal[nb]);
        }
        bf16x8 bq[4];
#pragma unroll
        for (int ct = 0; ct < 4; ++ct) {
            const int t = ct * 16 + l16;
            const int s = (t & 7) << 3;
            bq[ct] = *(const bf16x8*)&qb[t * 256 + ((it * 32 + quad * 8) ^ s)];
        }
        __builtin_amdgcn_s_setprio(1);
#pragma unroll
        for (int rt = 0; rt < 4; ++rt)
#pragma unroll
            for (int ct = 0; ct < 4; ++ct) {
                acc[rt][ct] = __builtin_amdgcn_mfma_f32_16x16x32_bf16(mah[cb][rt], bq[ct], acc[rt][ct], 0, 0, 0);
                acc[rt][ct] = __builtin_amdgcn_mfma_f32_16x16x32_bf16(mal[cb][rt], bq[ct], acc[rt][ct], 0, 0, 0);
            }
        __builtin_amdgcn_s_setprio(0);
    }

    float* ob = out + (size_t)b * 256 * NTOK;
#pragma unroll
    for (int rt = 0; rt < 4; ++rt)
#pragma unroll
        for (int ct = 0; ct < 4; ++ct) {
            const int t = ct * 16 + l16;
#pragma unroll
            for (int r = 0; r < 4; ++r) {
                const int o = wave * 64 + rt * 16 + quad * 4 + r;
                ob[(size_t)o * NTOK + n0 + t] = acc[rt][ct][r] + bout[o];
            }
        }
}

extern "C" void kernel_launch(void* const* d_in, const int* in_sizes, int n_in,
                              void* d_out, int out_size, void* d_ws, size_t ws_size,
                              hipStream_t stream)
{
    (void)in_sizes; (void)n_in; (void)out_size; (void)ws_size;
    const float* x    = (const float*)d_in[0];
    const float* wqkv = (const float*)d_in[1];
    const float* bqkv = (const float*)d_in[2];
    const float* wout = (const float*)d_in[3];
    const float* bout = (const float*)d_in[4];
    float* out = (float*)d_out;
    float* ws  = (float*)d_ws;

    unsigned short* whi = (unsigned short*)(ws + WHI_OFF);
    unsigned short* wlo = (unsigned short*)(ws + WLO_OFF);
    float*          ctx = ws + CTX_OFF;
    float*          zs  = ws + Z_OFF;
    unsigned short* mhi = (unsigned short*)(ws + MHI_OFF);
    unsigned short* mlo = (unsigned short*)(ws + MLO_OFF);

    hipMemsetAsync(ctx, 0, (65536 + 2048) * sizeof(float), stream);
    splitw_k<<<96, 256, 0, stream>>>(wqkv, whi, wlo);
    kv_ctx_k<<<512, 256, 0, stream>>>(x, whi, wlo, bqkv, ctx, zs);
    build_m_k<<<64, 256, 0, stream>>>(ctx, zs, wout, mhi, mlo);
    final_k<<<2048, 256, 0, stream>>>(x, whi, wlo, bqkv, mhi, mlo, bout, out);
}